// Round 16
// baseline (201.358 us; speedup 1.0000x reference)
//
#include <hip/hip_runtime.h>
#include <math.h>

constexpr int S = 2048, D = 1024, H = 16;
constexpr float QSCL = 0.18033688011112042f;   // log2(e) / sqrt(64)

typedef __attribute__((ext_vector_type(8))) short bf16x8;
typedef __attribute__((ext_vector_type(4))) short s16x4;
typedef __attribute__((ext_vector_type(4))) float f32x4;
typedef __attribute__((ext_vector_type(16))) float f32x16;

#define MFMA16(a,b,c) __builtin_amdgcn_mfma_f32_16x16x32_bf16(a,b,c,0,0,0)
#define MFMA32(a,b,c) __builtin_amdgcn_mfma_f32_32x32x16_bf16(a,b,c,0,0,0)

#if __has_builtin(__builtin_amdgcn_exp2f)
#define EXP2(x) __builtin_amdgcn_exp2f(x)
#else
#define EXP2(x) exp2f(x)
#endif

#define GLDS16(g, l) __builtin_amdgcn_global_load_lds( \
    (const __attribute__((address_space(1))) unsigned*)(const void*)(g), \
    (__attribute__((address_space(3))) unsigned*)(void*)(l), 16, 0, 0)

__device__ inline short f2bf(float f) {
    union { float f; unsigned u; } c; c.f = f;
    unsigned u = c.u + 0x7fffu + ((c.u >> 16) & 1u);
    return (short)(u >> 16);
}

// ---------------------------------------------------------------------------
// Convert x and the 4 weight matrices to bf16 (RNE). wq..wf land contiguous.
// ---------------------------------------------------------------------------
__global__ __launch_bounds__(256)
void conv_pack(const float* __restrict__ x,  const float* __restrict__ wq,
               const float* __restrict__ wk, const float* __restrict__ wv,
               const float* __restrict__ wf,
               short* __restrict__ xb,  short* __restrict__ wqb,
               short* __restrict__ wkb, short* __restrict__ wvb,
               short* __restrict__ wfb)
{
    int i = blockIdx.x * 256 + threadIdx.x;
    const float* s; short* d; int o;
    if (i < 2097152) { s = x; d = xb; o = i; }
    else {
        int j = i - 2097152; int wsel = j >> 18; o = j & 262143;
        s = wsel == 0 ? wq : wsel == 1 ? wk : wsel == 2 ? wv : wf;
        d = wsel == 0 ? wqb : wsel == 1 ? wkb : wsel == 2 ? wvb : wfb;
    }
    float4 v = ((const float4*)s)[o];
    s16x4 r; r.x = f2bf(v.x); r.y = f2bf(v.y); r.z = f2bf(v.z); r.w = f2bf(v.w);
    ((s16x4*)d)[o] = r;
}

// ---------------------------------------------------------------------------
// Per-lane mask column words (fallback path). Bit r of word(lane) =
// mask[bb][grp*32+(lane&31)][tile*64 + (r&3)+8*((r>>2)&3)+32*(r>>4)+4*(lane>>5)]
// ---------------------------------------------------------------------------
__global__ __launch_bounds__(256)
void conv_maskcol(const int* __restrict__ m, unsigned* __restrict__ o)
{
    int gid = blockIdx.x * 256 + threadIdx.x;      // 2048 blocks -> 524288
    int lane = gid & 63;
    int tile = (gid >> 6) & 31;
    int grp  = (gid >> 11) & 63;
    int bb   = gid >> 17;
    int qrow = grp * 32 + (lane & 31);
    int h = lane >> 5;
    const int* base = m + (size_t)bb * S * S + (size_t)qrow * S + tile * 64 + 4 * h;
    unsigned wbits = 0;
#pragma unroll
    for (int a = 0; a < 8; ++a) {
        int4 v = *(const int4*)(base + 8 * (a & 3) + 32 * (a >> 2));
        wbits |= (v.x != 0 ? 1u : 0u) << (4 * a);
        wbits |= (v.y != 0 ? 1u : 0u) << (4 * a + 1);
        wbits |= (v.z != 0 ? 1u : 0u) << (4 * a + 2);
        wbits |= (v.w != 0 ? 1u : 0u) << (4 * a + 3);
    }
    o[gid] = wbits;
}

// ---------------------------------------------------------------------------
// Mask bias A-fragments (frag path): per (b, qgrp32, kblk32) a 32x32 block of
// bf16 {0 keep, -2992 masked} in MFMA32 A-operand layout, split into 2 frags.
// Lane l, elem jj of frag f: maskval[key = kt*32+(l&31)][q = qg*32+f*16+8*(l>>5)+jj]
// (R9/R12-proven)
// ---------------------------------------------------------------------------
__global__ __launch_bounds__(256)
void conv_maskfrag(const int* __restrict__ m, short* __restrict__ o)
{
    int u = blockIdx.x * 4 + (threadIdx.x >> 6);   // 0..16383
    int l = threadIdx.x & 63;
    int l31 = l & 31, h = l >> 5;
    int kt = u & 63, qg = (u >> 6) & 63, bb = u >> 12;
    int key = kt * 32 + l31;
    const int* mb = m + (size_t)bb * S * S + key;
    size_t ob = (size_t)u * 1024 + l * 8;
#pragma unroll
    for (int f = 0; f < 2; ++f) {
        bf16x8 frag;
#pragma unroll
        for (int jj = 0; jj < 8; ++jj) {
            int q = qg * 32 + f * 16 + 8 * h + jj;
            frag[jj] = mb[(size_t)q * S] != 0 ? (short)0 : (short)0xC53B;  // -2992
        }
        *(bf16x8*)(o + ob + f * 512) = frag;
    }
}

// ---------------------------------------------------------------------------
// Fused QKV GEMM, 128x128 tile, BK=64, global_load_lds + XOR swizzle.
// C[8192,3072] = x @ [Wq;Wk;Wv]^T. grid (64, 24); block 256 = 4 waves (2x2).
// Epilogue: q scaled by log2e/8 -> [B,H,S,64]; k -> [B,H,S,64]; v -> [B,H,64,S].
// ---------------------------------------------------------------------------
__global__ __launch_bounds__(256, 3)
void qkv_mfma(const short* __restrict__ xb, const short* __restrict__ wcat,
              const float* __restrict__ bq, const float* __restrict__ bk,
              const float* __restrict__ bv,
              short* __restrict__ qo, short* __restrict__ ko, short* __restrict__ vto)
{
    __shared__ short As[128 * 64];
    __shared__ short Bs[128 * 64];
    const int t = threadIdx.x, lane = t & 63;
    const int w = __builtin_amdgcn_readfirstlane(t >> 6);
    const int lr = lane & 15, lg = lane >> 4;
    const int wr = w >> 1, wc = w & 1;
    const int m0 = blockIdx.x * 128, n0 = blockIdx.y * 128;

    const int srow = t >> 3;                            // 0..31
    const int scol = ((t & 7) ^ (srow & 7)) * 8;        // pre-swizzled col group
    const short* asrc = xb   + (size_t)(m0 + srow) * 1024 + scol;
    const short* bsrc = wcat + (size_t)(n0 + srow) * 1024 + scol;
    char* aldst = (char*)As + w * 1024;                 // HW adds lane*16
    char* bldst = (char*)Bs + w * 1024;

    f32x4 z = {0.f, 0.f, 0.f, 0.f};
    f32x4 acc[4][4];
#pragma unroll
    for (int i = 0; i < 4; ++i)
#pragma unroll
        for (int jj = 0; jj < 4; ++jj) acc[i][jj] = z;

    for (int kt = 0; kt < 1024; kt += 64) {
        __syncthreads();
        GLDS16(asrc + kt,             aldst);
        GLDS16(asrc + kt + 32 * 1024, aldst + 4096);
        GLDS16(asrc + kt + 64 * 1024, aldst + 8192);
        GLDS16(asrc + kt + 96 * 1024, aldst + 12288);
        GLDS16(bsrc + kt,             bldst);
        GLDS16(bsrc + kt + 32 * 1024, bldst + 4096);
        GLDS16(bsrc + kt + 64 * 1024, bldst + 8192);
        GLDS16(bsrc + kt + 96 * 1024, bldst + 12288);
        __syncthreads();
#pragma unroll
        for (int ks = 0; ks < 2; ++ks) {
            bf16x8 af[4], bfr[4];
#pragma unroll
            for (int fi = 0; fi < 4; ++fi) {
                const int ra = wr * 64 + fi * 16 + lr;
                af[fi] = *(const bf16x8*)((const char*)As + ra * 128 +
                          ((ks * 64 + lg * 16) ^ ((ra & 7) << 4)));
                const int rb = wc * 64 + fi * 16 + lr;
                bfr[fi] = *(const bf16x8*)((const char*)Bs + rb * 128 +
                          ((ks * 64 + lg * 16) ^ ((rb & 7) << 4)));
            }
#pragma unroll
            for (int fi = 0; fi < 4; ++fi)
#pragma unroll
                for (int fj = 0; fj < 4; ++fj)
                    acc[fi][fj] = MFMA16(af[fi], bfr[fj], acc[fi][fj]);
        }
    }

    const int bb = m0 >> 11;
    const int ssb = (m0 & (S - 1)) + wr * 64 + lg * 4;
    const int mat = n0 >> 10;
    const int nbase = (n0 & 1023) + wc * 64;

    if (mat == 0) {
#pragma unroll
        for (int fj = 0; fj < 4; ++fj) {
            const int nl = nbase + fj * 16 + lr, hh = nl >> 6, hd = nl & 63;
            const float bi = bq[nl];
#pragma unroll
            for (int fi = 0; fi < 4; ++fi)
#pragma unroll
                for (int r = 0; r < 4; ++r)
                    qo[(((size_t)bb * H + hh) * S + ssb + fi * 16 + r) * 64 + hd] =
                        f2bf((acc[fi][fj][r] + bi) * QSCL);
        }
    } else if (mat == 1) {
#pragma unroll
        for (int fj = 0; fj < 4; ++fj) {
            const int nl = nbase + fj * 16 + lr, hh = nl >> 6, hd = nl & 63;
            const float bi = bk[nl];
#pragma unroll
            for (int fi = 0; fi < 4; ++fi)
#pragma unroll
                for (int r = 0; r < 4; ++r)
                    ko[(((size_t)bb * H + hh) * S + ssb + fi * 16 + r) * 64 + hd] =
                        f2bf(acc[fi][fj][r] + bi);
        }
    } else {
#pragma unroll
        for (int fj = 0; fj < 4; ++fj) {
            const int nl = nbase + fj * 16 + lr, hh = nl >> 6, hd = nl & 63;
            const float bi = bv[nl];
#pragma unroll
            for (int fi = 0; fi < 4; ++fi) {
                s16x4 pk;
#pragma unroll
                for (int r = 0; r < 4; ++r) pk[r] = f2bf(acc[fi][fj][r] + bi);
                *(s16x4*)(vto + (((size_t)bb * H + hh) * 64 + hd) * S + ssb + fi * 16) = pk;
            }
        }
    }
}

// ---------------------------------------------------------------------------
// Flash attention v9: swapped-QK 32x32 MFMA, native exp2, VALU li (no Lacc
// MFMA), mask via bias-fragment MFMA accumulator init (USEFRAG=1, zero VALU
// select) or select path (USEFRAG=0). Frags register-prefetched 1 tile ahead.
// 4 blocks/CU (VGPR ~64-76 << 128, no remat hazard; asm volatile).
// 4 waves x 32 q = 128 q. grid 1024 (XCD-grouped).
// ---------------------------------------------------------------------------
template<int USEFRAG>
__global__ __launch_bounds__(256, 4)
void attn_mfma9(const short* __restrict__ qg, const short* __restrict__ kg,
                const short* __restrict__ vtg,
                const unsigned* __restrict__ mcol,
                const short* __restrict__ mfrag,
                short* __restrict__ hc)
{
    __shared__ short Kl[2][64 * 64];
    __shared__ short Vl[2][64 * 64];

    const int t = threadIdx.x, lane = t & 63;
    const int w = __builtin_amdgcn_readfirstlane(t >> 6);
    const int l31 = lane & 31, h = lane >> 5;

    const int id = blockIdx.x;
    const int xcd = id & 7, j = id >> 3;
    const int bh = xcd + 8 * (j >> 4);
    const int q0 = (j & 15) * 128;
    const int bb = bh >> 4, hh = bh & 15;

    const short* qb  = qg  + (size_t)bh * S * 64;
    const short* kb  = kg  + (size_t)bh * S * 64;
    const short* vtb = vtg + (size_t)bh * 64 * S;
    const int bqg = bb * 64 + (q0 >> 5) + w;
    const unsigned* mc = mcol + (size_t)bqg * 32 * 64 + lane;
    const short* mfb = mfrag + (size_t)bqg * 65536 + lane * 8;

    const int qrow = q0 + w * 32 + l31;
    bf16x8 qf[4];
#pragma unroll
    for (int ds = 0; ds < 4; ++ds)
        qf[ds] = *(const bf16x8*)(qb + (size_t)qrow * 64 + ds * 16 + 8 * h);

    // identity B fragments for the mask-bias MFMAs
    bf16x8 idB0, idB1;
#pragma unroll
    for (int jj = 0; jj < 8; ++jj) {
        idB0[jj] = (8 * h + jj == l31)      ? (short)0x3F80 : (short)0;
        idB1[jj] = (8 * h + jj + 16 == l31) ? (short)0x3F80 : (short)0;
    }

    const int sk = t >> 3;                                    // staging row 0..31
    const int soff = (((t & 7) * 16) ^ ((sk & 7) << 4)) >> 1; // pre-swizzled src elem
    const int rbyte = l31 * 128;
    const int sz = (lane & 7) << 4;

    f32x16 z16;
#pragma unroll
    for (int i = 0; i < 16; ++i) z16[i] = 0.f;
    f32x16 O0 = z16, O1 = z16;
    float li = 0.f;

    auto issue_stage = [&](int kt, int buf) {
        const short* ks0 = kb + (size_t)(kt + sk) * 64 + soff;
        const short* vs0 = vtb + (size_t)sk * S + kt + soff;
        char* kB = (char*)&Kl[buf][0] + w * 1024;
        char* vB = (char*)&Vl[buf][0] + w * 1024;
        GLDS16(ks0, kB);
        GLDS16(ks0 + 32 * 64, kB + 4096);
        GLDS16(vs0, vB);
        GLDS16(vs0 + (size_t)32 * S, vB + 4096);
    };

    // tile-0 prefetch of mask data into registers
    bf16x8 fr0, fr1, fr2, fr3;
    unsigned mcw = 0;
    if (USEFRAG) {
        fr0 = *(const bf16x8*)(mfb);
        fr1 = *(const bf16x8*)(mfb + 512);
        fr2 = *(const bf16x8*)(mfb + 1024);
        fr3 = *(const bf16x8*)(mfb + 1536);
    } else {
        mcw = mc[0];
    }

    issue_stage(0, 0);
    __syncthreads();

    for (int tile = 0; tile < 32; ++tile) {
        const int cur = tile & 1;
        // prefetch next tile: K/V -> LDS, mask frags/word -> registers
        bf16x8 nf0, nf1, nf2, nf3;
        unsigned mcn = 0;
        if (tile < 31) {
            issue_stage((tile + 1) * 64, cur ^ 1);
            if (USEFRAG) {
                const short* mfn = mfb + (tile + 1) * 2048;
                nf0 = *(const bf16x8*)(mfn);
                nf1 = *(const bf16x8*)(mfn + 512);
                nf2 = *(const bf16x8*)(mfn + 1024);
                nf3 = *(const bf16x8*)(mfn + 1536);
            } else {
                mcn = mc[(tile + 1) * 64];
            }
        }

        // ---- accumulator init: mask bias (frag path) or zero (select path)
        f32x16 s0, s1;
        if (USEFRAG) {
            s0 = MFMA32(fr0, idB0, z16);
            s0 = MFMA32(fr1, idB1, s0);
            s1 = MFMA32(fr2, idB0, z16);
            s1 = MFMA32(fr3, idB1, s1);
        } else {
            s0 = z16; s1 = z16;
        }

        // ---- QK^T (swapped): lane owns q-row l31
        const char* Kb = (const char*)&Kl[cur][0];
#pragma unroll
        for (int ds = 0; ds < 4; ++ds) {
            const int off = ((ds * 32 + h * 16) ^ sz);
            bf16x8 a0 = *(const bf16x8*)(Kb + rbyte + off);
            bf16x8 a1 = *(const bf16x8*)(Kb + 4096 + rbyte + off);
            s0 = MFMA32(a0, qf[ds], s0);
            s1 = MFMA32(a1, qf[ds], s1);
        }

        // ---- p = 2^s (masked s ~ -2992 -> 0) ; li += p ; pack ; PV
        const char* Vb = (const char*)&Vl[cur][0];
#pragma unroll
        for (int ks = 0; ks < 4; ++ks) {
            const int rb = (ks < 2) ? ks * 8 : (ks - 2) * 8;
            const int wb = (ks < 2) ? rb : 16 + rb;
            float pv[8];
#pragma unroll
            for (int jj = 0; jj < 8; ++jj) {
                float sv = (ks < 2) ? s0[rb + jj] : s1[rb + jj];
                if (!USEFRAG)
                    sv = (mcw & (1u << (wb + jj))) ? sv : -INFINITY;
                pv[jj] = EXP2(sv);
                li += pv[jj];
            }
            int w0a, w1a, w0b, w1b;
            asm volatile("v_cvt_pk_bf16_f32 %0, %1, %2" : "=v"(w0a) : "v"(pv[0]), "v"(pv[1]));
            asm volatile("v_cvt_pk_bf16_f32 %0, %1, %2" : "=v"(w1a) : "v"(pv[2]), "v"(pv[3]));
            asm volatile("v_cvt_pk_bf16_f32 %0, %1, %2" : "=v"(w0b) : "v"(pv[4]), "v"(pv[5]));
            asm volatile("v_cvt_pk_bf16_f32 %0, %1, %2" : "=v"(w1b) : "v"(pv[6]), "v"(pv[7]));
            asm volatile("v_permlane32_swap_b32 %0, %1" : "+v"(w0a), "+v"(w0b));
            asm volatile("v_permlane32_swap_b32 %0, %1" : "+v"(w1a), "+v"(w1b));
            union { int i[4]; bf16x8 v; } pf;
            pf.i[0] = w0a; pf.i[1] = w1a; pf.i[2] = w0b; pf.i[3] = w1b;

            const int koff = ((ks * 32 + h * 16) ^ sz);
            bf16x8 v0 = *(const bf16x8*)(Vb + rbyte + koff);
            bf16x8 v1 = *(const bf16x8*)(Vb + 4096 + rbyte + koff);
            O0 = MFMA32(pf.v, v0, O0);
            O1 = MFMA32(pf.v, v1, O1);
        }

        if (tile < 31) {
            if (USEFRAG) { fr0 = nf0; fr1 = nf1; fr2 = nf2; fr3 = nf3; }
            else mcw = mcn;
        }
        __syncthreads();
    }

    // ---- epilogue: combine half-row sums, broadcast 1/li to output regs
    li += __shfl_xor(li, 32);             // full row-sum for q-row l31
    const float inv = 1.f / li;
    const int ib = __builtin_bit_cast(int, inv);
    const size_t outb = (size_t)bb * S * D + (size_t)hh * 64;
#pragma unroll
    for (int r = 0; r < 16; ++r) {
        const int qp = (r & 3) + 8 * (r >> 2);
        const int vlo = __builtin_amdgcn_readlane(ib, qp);
        const int vhi = __builtin_amdgcn_readlane(ib, qp + 4);
        const float ir = h ? __builtin_bit_cast(float, vhi)
                           : __builtin_bit_cast(float, vlo);
        const int row = q0 + w * 32 + qp + 4 * h;
        hc[outb + (size_t)row * D + l31]      = f2bf(O0[r] * ir);
        hc[outb + (size_t)row * D + 32 + l31] = f2bf(O1[r] * ir);
    }
}

// ---------------------------------------------------------------------------
// Output projection, 128x128 tile, fp32 out. grid (64, 8); block 256.
// ---------------------------------------------------------------------------
__global__ __launch_bounds__(256, 3)
void proj_mfma(const short* __restrict__ hb, const short* __restrict__ wfb,
               const float* __restrict__ bfp, float* __restrict__ out)
{
    __shared__ short As[128 * 64];
    __shared__ short Bs[128 * 64];
    const int t = threadIdx.x, lane = t & 63;
    const int w = __builtin_amdgcn_readfirstlane(t >> 6);
    const int lr = lane & 15, lg = lane >> 4;
    const int wr = w >> 1, wc = w & 1;
    const int m0 = blockIdx.x * 128, n0 = blockIdx.y * 128;

    const int srow = t >> 3;
    const int scol = ((t & 7) ^ (srow & 7)) * 8;
    const short* asrc = hb  + (size_t)(m0 + srow) * 1024 + scol;
    const short* bsrc = wfb + (size_t)(n0 + srow) * 1024 + scol;
    char* aldst = (char*)As + w * 1024;
    char* bldst = (char*)Bs + w * 1024;

    f32x4 z = {0.f, 0.f, 0.f, 0.f};
    f32x4 acc[4][4];
#pragma unroll
    for (int i = 0; i < 4; ++i)
#pragma unroll
        for (int jj = 0; jj < 4; ++jj) acc[i][jj] = z;

    for (int kt = 0; kt < 1024; kt += 64) {
        __syncthreads();
        GLDS16(asrc + kt,             aldst);
        GLDS16(asrc + kt + 32 * 1024, aldst + 4096);
        GLDS16(asrc + kt + 64 * 1024, aldst + 8192);
        GLDS16(asrc + kt + 96 * 1024, aldst + 12288);
        GLDS16(bsrc + kt,             bldst);
        GLDS16(bsrc + kt + 32 * 1024, bldst + 4096);
        GLDS16(bsrc + kt + 64 * 1024, bldst + 8192);
        GLDS16(bsrc + kt + 96 * 1024, bldst + 12288);
        __syncthreads();
#pragma unroll
        for (int ks = 0; ks < 2; ++ks) {
            bf16x8 af[4], bfr[4];
#pragma unroll
            for (int fi = 0; fi < 4; ++fi) {
                const int ra = wr * 64 + fi * 16 + lr;
                af[fi] = *(const bf16x8*)((const char*)As + ra * 128 +
                          ((ks * 64 + lg * 16) ^ ((ra & 7) << 4)));
                const int rb = wc * 64 + fi * 16 + lr;
                bfr[fi] = *(const bf16x8*)((const char*)Bs + rb * 128 +
                          ((ks * 64 + lg * 16) ^ ((rb & 7) << 4)));
            }
#pragma unroll
            for (int fi = 0; fi < 4; ++fi)
#pragma unroll
                for (int fj = 0; fj < 4; ++fj)
                    acc[fi][fj] = MFMA16(af[fi], bfr[fj], acc[fi][fj]);
        }
    }

#pragma unroll
    for (int fj = 0; fj < 4; ++fj) {
        const int nl = n0 + wc * 64 + fj * 16 + lr;
        const float bi = bfp[nl];
#pragma unroll
        for (int fi = 0; fi < 4; ++fi)
#pragma unroll
            for (int r = 0; r < 4; ++r)
                out[(size_t)(m0 + wr * 64 + fi * 16 + lg * 4 + r) * 1024 + nl] =
                    acc[fi][fj][r] + bi;
    }
}

// ---------------------------------------------------------------------------
extern "C" void kernel_launch(void* const* d_in, const int* in_sizes, int n_in,
                              void* d_out, int out_size, void* d_ws, size_t ws_size,
                              hipStream_t stream)
{
    const float* x  = (const float*)d_in[0];
    const int* mask = (const int*)d_in[1];
    const float* Wq = (const float*)d_in[2];
    const float* bq = (const float*)d_in[3];
    const float* Wk = (const float*)d_in[4];
    const float* bk = (const float*)d_in[5];
    const float* Wv = (const float*)d_in[6];
    const float* bv = (const float*)d_in[7];
    const float* Wf = (const float*)d_in[8];
    const float* bf = (const float*)d_in[9];
    float* out = (float*)d_out;

    char* p = (char*)d_ws;
    short* xb  = (short*)p; p += 16777216;                       // x bf16
    short* wqb = (short*)p; p += 2097152;                        // [Wq;Wk;Wv;Wf] bf16
    short* wkb = (short*)p; p += 2097152;
    short* wvb = (short*)p; p += 2097152;
    short* wfb = (short*)p; p += 2097152;
    short* qb  = (short*)p; p += 16777216;                       // [B,H,S,64]
    short* kb  = (short*)p; p += 16777216;                       // [B,H,S,64]
    short* vtb = (short*)p; p += 16777216;                       // [B,H,64,S]
    short* hcb = (short*)p; p += 16777216;                       // [B,S,D]
    unsigned* mcol = (unsigned*)p; p += 2097152;                 // mask column words
    short* mfrag = (short*)p; p += 33554432;                     // mask bias A-frags
    const size_t need_frag = (size_t)(p - (char*)d_ws);

    const bool usefrag = ws_size >= need_frag;

    conv_pack<<<12288, 256, 0, stream>>>(x, Wq, Wk, Wv, Wf, xb, wqb, wkb, wvb, wfb);
    qkv_mfma<<<dim3(64, 24), 256, 0, stream>>>(xb, wqb, bq, bk, bv, qb, kb, vtb);
    if (usefrag) {
        conv_maskfrag<<<4096, 256, 0, stream>>>(mask, mfrag);
        attn_mfma9<1><<<1024, 256, 0, stream>>>(qb, kb, vtb, mcol, mfrag, hcb);
    } else {
        conv_maskcol<<<2048, 256, 0, stream>>>(mask, mcol);
        attn_mfma9<0><<<1024, 256, 0, stream>>>(qb, kb, vtb, mcol, mfrag, hcb);
    }
    proj_mfma<<<dim3(64, 8), 256, 0, stream>>>(hcb, wfb, bf, out);
}

// Round 17
// 194.943 us; speedup vs baseline: 1.0329x; 1.0329x over previous
//
#include <hip/hip_runtime.h>
#include <math.h>

constexpr int S = 2048, D = 1024, H = 16;
constexpr float QSCL = 0.18033688011112042f;   // log2(e) / sqrt(64)

typedef __attribute__((ext_vector_type(8))) short bf16x8;
typedef __attribute__((ext_vector_type(4))) short s16x4;
typedef __attribute__((ext_vector_type(4))) float f32x4;
typedef __attribute__((ext_vector_type(16))) float f32x16;

#define MFMA16(a,b,c) __builtin_amdgcn_mfma_f32_16x16x32_bf16(a,b,c,0,0,0)
#define MFMA32(a,b,c) __builtin_amdgcn_mfma_f32_32x32x16_bf16(a,b,c,0,0,0)

#if __has_builtin(__builtin_amdgcn_exp2f)
#define EXP2(x) __builtin_amdgcn_exp2f(x)
#else
#define EXP2(x) exp2f(x)
#endif

#define GLDS16(g, l) __builtin_amdgcn_global_load_lds( \
    (const __attribute__((address_space(1))) unsigned*)(const void*)(g), \
    (__attribute__((address_space(3))) unsigned*)(void*)(l), 16, 0, 0)

__device__ inline short f2bf(float f) {
    union { float f; unsigned u; } c; c.f = f;
    unsigned u = c.u + 0x7fffu + ((c.u >> 16) & 1u);
    return (short)(u >> 16);
}

// ---------------------------------------------------------------------------
// Convert x and the 4 weight matrices to bf16 (RNE). wq..wf land contiguous.
// ---------------------------------------------------------------------------
__global__ __launch_bounds__(256)
void conv_pack(const float* __restrict__ x,  const float* __restrict__ wq,
               const float* __restrict__ wk, const float* __restrict__ wv,
               const float* __restrict__ wf,
               short* __restrict__ xb,  short* __restrict__ wqb,
               short* __restrict__ wkb, short* __restrict__ wvb,
               short* __restrict__ wfb)
{
    int i = blockIdx.x * 256 + threadIdx.x;
    const float* s; short* d; int o;
    if (i < 2097152) { s = x; d = xb; o = i; }
    else {
        int j = i - 2097152; int wsel = j >> 18; o = j & 262143;
        s = wsel == 0 ? wq : wsel == 1 ? wk : wsel == 2 ? wv : wf;
        d = wsel == 0 ? wqb : wsel == 1 ? wkb : wsel == 2 ? wvb : wfb;
    }
    float4 v = ((const float4*)s)[o];
    s16x4 r; r.x = f2bf(v.x); r.y = f2bf(v.y); r.z = f2bf(v.z); r.w = f2bf(v.w);
    ((s16x4*)d)[o] = r;
}

// ---------------------------------------------------------------------------
// Per-lane mask column words. Bit r of word(lane) =
// mask[bb][grp*32+(lane&31)][tile*64 + (r&3)+8*((r>>2)&3)+32*(r>>4)+4*(lane>>5)]
// (coalesced int4 reads; R8/R15-proven)
// ---------------------------------------------------------------------------
__global__ __launch_bounds__(256)
void conv_maskcol(const int* __restrict__ m, unsigned* __restrict__ o)
{
    int gid = blockIdx.x * 256 + threadIdx.x;      // 2048 blocks -> 524288
    int lane = gid & 63;
    int tile = (gid >> 6) & 31;
    int grp  = (gid >> 11) & 63;
    int bb   = gid >> 17;
    int qrow = grp * 32 + (lane & 31);
    int h = lane >> 5;
    const int* base = m + (size_t)bb * S * S + (size_t)qrow * S + tile * 64 + 4 * h;
    unsigned wbits = 0;
#pragma unroll
    for (int a = 0; a < 8; ++a) {
        int4 v = *(const int4*)(base + 8 * (a & 3) + 32 * (a >> 2));
        wbits |= (v.x != 0 ? 1u : 0u) << (4 * a);
        wbits |= (v.y != 0 ? 1u : 0u) << (4 * a + 1);
        wbits |= (v.z != 0 ? 1u : 0u) << (4 * a + 2);
        wbits |= (v.w != 0 ? 1u : 0u) << (4 * a + 3);
    }
    o[gid] = wbits;
}

// ---------------------------------------------------------------------------
// Fused QKV GEMM v2: 256x128 tile, BK=32, 3-buffer LDS pipeline with 2-K-tile
// lookahead, counted vmcnt(3) (never drained in steady state), raw s_barrier.
// 512 threads = 8 waves (4M x 2N), per-wave 64x64 output.
// grid (32, 24). Epilogue: q*QSCL -> [B,H,S,64]; k -> [B,H,S,64]; v -> [B,H,64,S].
// ---------------------------------------------------------------------------
__global__ __launch_bounds__(512, 2)
void qkv_p3(const short* __restrict__ xb, const short* __restrict__ wcat,
            const float* __restrict__ bq, const float* __restrict__ bk,
            const float* __restrict__ bv,
            short* __restrict__ qo, short* __restrict__ ko, short* __restrict__ vto)
{
    __shared__ char Lds[73728];          // A: 3 x 16KB, B: 3 x 8KB

    const int t = threadIdx.x, lane = t & 63;
    const int wu = __builtin_amdgcn_readfirstlane(t >> 6);   // wave 0..7
    const int lr = lane & 15, lg = lane >> 4;
    const int wr = wu >> 1, wc = wu & 1;
    const int m0 = blockIdx.x * 256, n0 = blockIdx.y * 128;

    // staging: per call 512 thr x 16B = 8KB = 128 rows of 64B.
    const int srow = t >> 2;                       // 0..127
    const int sw   = ((t & 3) ^ (srow & 3)) * 8;   // pre-swizzled col elems
    const short* asrc0 = xb   + (size_t)(m0 + srow) * 1024 + sw;
    const short* bsrc0 = wcat + (size_t)(n0 + srow) * 1024 + sw;

    // frag-read constants
    const int colA  = (lg * 16) ^ ((lr & 3) << 4);   // byte within 64B row
    const int aRowB = (wr * 64 + lr) * 64;
    const int bRowB = (wc * 64 + lr) * 64;

    f32x4 z = {0.f, 0.f, 0.f, 0.f};
    f32x4 acc[4][4];
#pragma unroll
    for (int i = 0; i < 4; ++i)
#pragma unroll
        for (int jj = 0; jj < 4; ++jj) acc[i][jj] = z;

    auto stage = [&](int k2, int buf2) {
        const int kofs = k2 * 32;
        char* ab = Lds + buf2 * 16384 + wu * 1024;
        char* bb = Lds + 49152 + buf2 * 8192 + wu * 1024;
        GLDS16(asrc0 + kofs, ab);
        GLDS16(asrc0 + kofs + 128 * 1024, ab + 8192);
        GLDS16(bsrc0 + kofs, bb);
    };

    // prologue: K0 -> buf0, K1 -> buf1 ; wait K0 (leave K1's 3 in flight)
    stage(0, 0);
    stage(1, 1);
    asm volatile("s_waitcnt vmcnt(3)" ::: "memory");
    __builtin_amdgcn_s_barrier();
    __builtin_amdgcn_sched_barrier(0);

    for (int k = 0; k < 32; ++k) {
        const int buf = k % 3;
        if (k + 2 < 32) stage(k + 2, (k + 2) % 3);

        const char* Ab = Lds + buf * 16384;
        const char* Bb = Lds + 49152 + buf * 8192;
        bf16x8 bfr[4], af[4];
#pragma unroll
        for (int fj = 0; fj < 4; ++fj)
            bfr[fj] = *(const bf16x8*)(Bb + bRowB + fj * 1024 + colA);
#pragma unroll
        for (int fi = 0; fi < 4; ++fi)
            af[fi] = *(const bf16x8*)(Ab + aRowB + fi * 1024 + colA);

        __builtin_amdgcn_s_setprio(1);
#pragma unroll
        for (int fi = 0; fi < 4; ++fi)
#pragma unroll
            for (int fj = 0; fj < 4; ++fj)
                acc[fi][fj] = MFMA16(af[fi], bfr[fj], acc[fi][fj]);
        __builtin_amdgcn_s_setprio(0);

        if (k < 30)       asm volatile("s_waitcnt vmcnt(3)" ::: "memory");
        else if (k == 30) asm volatile("s_waitcnt vmcnt(0)" ::: "memory");
        __builtin_amdgcn_s_barrier();
        __builtin_amdgcn_sched_barrier(0);
    }

    // epilogue (proven form; wr in 0..3)
    const int bb = m0 >> 11;
    const int ssb = (m0 & 2047) + wr * 64 + lg * 4;
    const int mat = n0 >> 10;
    const int nbase = (n0 & 1023) + wc * 64;

    if (mat == 0) {
#pragma unroll
        for (int fj = 0; fj < 4; ++fj) {
            const int nl = nbase + fj * 16 + lr, hh = nl >> 6, hd = nl & 63;
            const float bi = bq[nl];
#pragma unroll
            for (int fi = 0; fi < 4; ++fi)
#pragma unroll
                for (int r = 0; r < 4; ++r)
                    qo[(((size_t)bb * H + hh) * S + ssb + fi * 16 + r) * 64 + hd] =
                        f2bf((acc[fi][fj][r] + bi) * QSCL);
        }
    } else if (mat == 1) {
#pragma unroll
        for (int fj = 0; fj < 4; ++fj) {
            const int nl = nbase + fj * 16 + lr, hh = nl >> 6, hd = nl & 63;
            const float bi = bk[nl];
#pragma unroll
            for (int fi = 0; fi < 4; ++fi)
#pragma unroll
                for (int r = 0; r < 4; ++r)
                    ko[(((size_t)bb * H + hh) * S + ssb + fi * 16 + r) * 64 + hd] =
                        f2bf(acc[fi][fj][r] + bi);
        }
    } else {
#pragma unroll
        for (int fj = 0; fj < 4; ++fj) {
            const int nl = nbase + fj * 16 + lr, hh = nl >> 6, hd = nl & 63;
            const float bi = bv[nl];
#pragma unroll
            for (int fi = 0; fi < 4; ++fi) {
                s16x4 pk;
#pragma unroll
                for (int r = 0; r < 4; ++r) pk[r] = f2bf(acc[fi][fj][r] + bi);
                *(s16x4*)(vto + (((size_t)bb * H + hh) * 64 + hd) * S + ssb + fi * 16) = pk;
            }
        }
    }
}

// ---------------------------------------------------------------------------
// Flash attention v8 (R15-proven): swapped-QK 32x32 MFMA, 16 MFMA/tile,
// select-mask from prefetched column word + native exp2, VALU li.
// 4 waves x 32 q = 128 q. grid 1024 (XCD-grouped).
// ---------------------------------------------------------------------------
__global__ __launch_bounds__(256, 3)
void attn_mfma8(const short* __restrict__ qg, const short* __restrict__ kg,
                const short* __restrict__ vtg,
                const unsigned* __restrict__ mcol,
                short* __restrict__ hc)
{
    __shared__ short Kl[2][64 * 64];
    __shared__ short Vl[2][64 * 64];

    const int t = threadIdx.x, lane = t & 63;
    const int w = __builtin_amdgcn_readfirstlane(t >> 6);
    const int l31 = lane & 31, h = lane >> 5;

    const int id = blockIdx.x;
    const int xcd = id & 7, j = id >> 3;
    const int bh = xcd + 8 * (j >> 4);
    const int q0 = (j & 15) * 128;
    const int bb = bh >> 4, hh = bh & 15;

    const short* qb  = qg  + (size_t)bh * S * 64;
    const short* kb  = kg  + (size_t)bh * S * 64;
    const short* vtb = vtg + (size_t)bh * 64 * S;
    const unsigned* mc = mcol + ((size_t)(bb * 64 + (q0 >> 5) + w)) * 32 * 64 + lane;

    const int qrow = q0 + w * 32 + l31;
    bf16x8 qf[4];
#pragma unroll
    for (int ds = 0; ds < 4; ++ds)
        qf[ds] = *(const bf16x8*)(qb + (size_t)qrow * 64 + ds * 16 + 8 * h);

    const int sk = t >> 3;                                    // staging row 0..31
    const int soff = (((t & 7) * 16) ^ ((sk & 7) << 4)) >> 1; // pre-swizzled src elem
    const int rbyte = l31 * 128;
    const int sz = (lane & 7) << 4;

    f32x16 z16;
#pragma unroll
    for (int i = 0; i < 16; ++i) z16[i] = 0.f;
    f32x16 O0 = z16, O1 = z16;
    float li = 0.f;

    auto issue_stage = [&](int kt, int buf) {
        const short* ks0 = kb + (size_t)(kt + sk) * 64 + soff;
        const short* vs0 = vtb + (size_t)sk * S + kt + soff;
        char* kB = (char*)&Kl[buf][0] + w * 1024;
        char* vB = (char*)&Vl[buf][0] + w * 1024;
        GLDS16(ks0, kB);
        GLDS16(ks0 + 32 * 64, kB + 4096);
        GLDS16(vs0, vB);
        GLDS16(vs0 + (size_t)32 * S, vB + 4096);
    };

    unsigned mcw = mc[0];
    issue_stage(0, 0);
    __syncthreads();

    for (int tile = 0; tile < 32; ++tile) {
        const int cur = tile & 1;
        unsigned mcn = 0;
        if (tile < 31) {
            issue_stage((tile + 1) * 64, cur ^ 1);
            mcn = mc[(tile + 1) * 64];
        }

        // ---- QK^T (swapped): lane owns q-row l31; acc starts at 0
        f32x16 s0 = z16, s1 = z16;
        const char* Kb = (const char*)&Kl[cur][0];
#pragma unroll
        for (int ds = 0; ds < 4; ++ds) {
            const int off = ((ds * 32 + h * 16) ^ sz);
            bf16x8 a0 = *(const bf16x8*)(Kb + rbyte + off);
            bf16x8 a1 = *(const bf16x8*)(Kb + 4096 + rbyte + off);
            s0 = MFMA32(a0, qf[ds], s0);
            s1 = MFMA32(a1, qf[ds], s1);
        }

        // ---- p = 2^(mask ? s : -inf) ; li += p ; pack ; PV
        const char* Vb = (const char*)&Vl[cur][0];
#pragma unroll
        for (int ks = 0; ks < 4; ++ks) {
            const int rb = (ks < 2) ? ks * 8 : (ks - 2) * 8;
            const int wb = (ks < 2) ? rb : 16 + rb;
            float pv[8];
#pragma unroll
            for (int jj = 0; jj < 8; ++jj) {
                float sv = (ks < 2) ? s0[rb + jj] : s1[rb + jj];
                sv = (mcw & (1u << (wb + jj))) ? sv : -INFINITY;
                pv[jj] = EXP2(sv);
                li += pv[jj];
            }
            int w0a, w1a, w0b, w1b;
            asm volatile("v_cvt_pk_bf16_f32 %0, %1, %2" : "=v"(w0a) : "v"(pv[0]), "v"(pv[1]));
            asm volatile("v_cvt_pk_bf16_f32 %0, %1, %2" : "=v"(w1a) : "v"(pv[2]), "v"(pv[3]));
            asm volatile("v_cvt_pk_bf16_f32 %0, %1, %2" : "=v"(w0b) : "v"(pv[4]), "v"(pv[5]));
            asm volatile("v_cvt_pk_bf16_f32 %0, %1, %2" : "=v"(w1b) : "v"(pv[6]), "v"(pv[7]));
            asm volatile("v_permlane32_swap_b32 %0, %1" : "+v"(w0a), "+v"(w0b));
            asm volatile("v_permlane32_swap_b32 %0, %1" : "+v"(w1a), "+v"(w1b));
            union { int i[4]; bf16x8 v; } pf;
            pf.i[0] = w0a; pf.i[1] = w1a; pf.i[2] = w0b; pf.i[3] = w1b;

            const int koff = ((ks * 32 + h * 16) ^ sz);
            bf16x8 v0 = *(const bf16x8*)(Vb + rbyte + koff);
            bf16x8 v1 = *(const bf16x8*)(Vb + 4096 + rbyte + koff);
            O0 = MFMA32(pf.v, v0, O0);
            O1 = MFMA32(pf.v, v1, O1);
        }

        if (tile < 31) mcw = mcn;
        __syncthreads();
    }

    // ---- epilogue: combine half-row sums, broadcast 1/li to output regs
    li += __shfl_xor(li, 32);             // full row-sum for q-row l31
    const float inv = 1.f / li;
    const int ib = __builtin_bit_cast(int, inv);
    const size_t outb = (size_t)bb * S * D + (size_t)hh * 64;
#pragma unroll
    for (int r = 0; r < 16; ++r) {
        const int qp = (r & 3) + 8 * (r >> 2);
        const int vlo = __builtin_amdgcn_readlane(ib, qp);
        const int vhi = __builtin_amdgcn_readlane(ib, qp + 4);
        const float ir = h ? __builtin_bit_cast(float, vhi)
                           : __builtin_bit_cast(float, vlo);
        const int row = q0 + w * 32 + qp + 4 * h;
        hc[outb + (size_t)row * D + l31]      = f2bf(O0[r] * ir);
        hc[outb + (size_t)row * D + 32 + l31] = f2bf(O1[r] * ir);
    }
}

// ---------------------------------------------------------------------------
// Output projection, 128x128 tile, fp32 out. grid (64, 8); block 256.
// ---------------------------------------------------------------------------
__global__ __launch_bounds__(256, 3)
void proj_mfma(const short* __restrict__ hb, const short* __restrict__ wfb,
               const float* __restrict__ bfp, float* __restrict__ out)
{
    __shared__ short As[128 * 64];
    __shared__ short Bs[128 * 64];
    const int t = threadIdx.x, lane = t & 63;
    const int w = __builtin_amdgcn_readfirstlane(t >> 6);
    const int lr = lane & 15, lg = lane >> 4;
    const int wr = w >> 1, wc = w & 1;
    const int m0 = blockIdx.x * 128, n0 = blockIdx.y * 128;

    const int srow = t >> 3;
    const int scol = ((t & 7) ^ (srow & 7)) * 8;
    const short* asrc = hb  + (size_t)(m0 + srow) * 1024 + scol;
    const short* bsrc = wfb + (size_t)(n0 + srow) * 1024 + scol;
    char* aldst = (char*)As + w * 1024;
    char* bldst = (char*)Bs + w * 1024;

    f32x4 z = {0.f, 0.f, 0.f, 0.f};
    f32x4 acc[4][4];
#pragma unroll
    for (int i = 0; i < 4; ++i)
#pragma unroll
        for (int jj = 0; jj < 4; ++jj) acc[i][jj] = z;

    for (int kt = 0; kt < 1024; kt += 64) {
        __syncthreads();
        GLDS16(asrc + kt,             aldst);
        GLDS16(asrc + kt + 32 * 1024, aldst + 4096);
        GLDS16(asrc + kt + 64 * 1024, aldst + 8192);
        GLDS16(asrc + kt + 96 * 1024, aldst + 12288);
        GLDS16(bsrc + kt,             bldst);
        GLDS16(bsrc + kt + 32 * 1024, bldst + 4096);
        GLDS16(bsrc + kt + 64 * 1024, bldst + 8192);
        GLDS16(bsrc + kt + 96 * 1024, bldst + 12288);
        __syncthreads();
#pragma unroll
        for (int ks = 0; ks < 2; ++ks) {
            bf16x8 af[4], bfr[4];
#pragma unroll
            for (int fi = 0; fi < 4; ++fi) {
                const int ra = wr * 64 + fi * 16 + lr;
                af[fi] = *(const bf16x8*)((const char*)As + ra * 128 +
                          ((ks * 64 + lg * 16) ^ ((ra & 7) << 4)));
                const int rb = wc * 64 + fi * 16 + lr;
                bfr[fi] = *(const bf16x8*)((const char*)Bs + rb * 128 +
                          ((ks * 64 + lg * 16) ^ ((rb & 7) << 4)));
            }
#pragma unroll
            for (int fi = 0; fi < 4; ++fi)
#pragma unroll
                for (int fj = 0; fj < 4; ++fj)
                    acc[fi][fj] = MFMA16(af[fi], bfr[fj], acc[fi][fj]);
        }
    }

#pragma unroll
    for (int fj = 0; fj < 4; ++fj) {
        const int nl = n0 + wc * 64 + fj * 16 + lr;
        const float bi = bfp[nl];
#pragma unroll
        for (int fi = 0; fi < 4; ++fi)
#pragma unroll
            for (int r = 0; r < 4; ++r)
                out[(size_t)(m0 + wr * 64 + fi * 16 + lg * 4 + r) * 1024 + nl] =
                    acc[fi][fj][r] + bi;
    }
}

// ---------------------------------------------------------------------------
extern "C" void kernel_launch(void* const* d_in, const int* in_sizes, int n_in,
                              void* d_out, int out_size, void* d_ws, size_t ws_size,
                              hipStream_t stream)
{
    const float* x  = (const float*)d_in[0];
    const int* mask = (const int*)d_in[1];
    const float* Wq = (const float*)d_in[2];
    const float* bq = (const float*)d_in[3];
    const float* Wk = (const float*)d_in[4];
    const float* bk = (const float*)d_in[5];
    const float* Wv = (const float*)d_in[6];
    const float* bv = (const float*)d_in[7];
    const float* Wf = (const float*)d_in[8];
    const float* bf = (const float*)d_in[9];
    float* out = (float*)d_out;

    char* p = (char*)d_ws;
    short* xb  = (short*)p; p += 16777216;                       // x bf16
    short* wqb = (short*)p; p += 2097152;                        // [Wq;Wk;Wv;Wf] bf16
    short* wkb = (short*)p; p += 2097152;
    short* wvb = (short*)p; p += 2097152;
    short* wfb = (short*)p; p += 2097152;
    short* qb  = (short*)p; p += 16777216;                       // [B,H,S,64]
    short* kb  = (short*)p; p += 16777216;                       // [B,H,S,64]
    short* vtb = (short*)p; p += 16777216;                       // [B,H,64,S]
    short* hcb = (short*)p; p += 16777216;                       // [B,S,D]
    unsigned* mcol = (unsigned*)p; p += 2097152;                 // mask column words

    conv_pack<<<12288, 256, 0, stream>>>(x, Wq, Wk, Wv, Wf, xb, wqb, wkb, wvb, wfb);
    conv_maskcol<<<2048, 256, 0, stream>>>(mask, mcol);
    qkv_p3<<<dim3(32, 24), 512, 0, stream>>>(xb, wqb, bq, bk, bv, qb, kb, vtb);
    attn_mfma8<<<1024, 256, 0, stream>>>(qb, kb, vtb, mcol, hcb);
    proj_mfma<<<dim3(64, 8), 256, 0, stream>>>(hcb, wfb, bf, out);
}

// Round 18
// 194.639 us; speedup vs baseline: 1.0345x; 1.0016x over previous
//
#include <hip/hip_runtime.h>
#include <math.h>

constexpr int S = 2048, D = 1024, H = 16;
constexpr float QSCL = 0.18033688011112042f;   // log2(e) / sqrt(64)

typedef __attribute__((ext_vector_type(8))) short bf16x8;
typedef __attribute__((ext_vector_type(4))) short s16x4;
typedef __attribute__((ext_vector_type(4))) float f32x4;
typedef __attribute__((ext_vector_type(16))) float f32x16;

#define MFMA16(a,b,c) __builtin_amdgcn_mfma_f32_16x16x32_bf16(a,b,c,0,0,0)
#define MFMA32(a,b,c) __builtin_amdgcn_mfma_f32_32x32x16_bf16(a,b,c,0,0,0)

#if __has_builtin(__builtin_amdgcn_exp2f)
#define EXP2(x) __builtin_amdgcn_exp2f(x)
#else
#define EXP2(x) exp2f(x)
#endif

#define GLDS16(g, l) __builtin_amdgcn_global_load_lds( \
    (const __attribute__((address_space(1))) unsigned*)(const void*)(g), \
    (__attribute__((address_space(3))) unsigned*)(void*)(l), 16, 0, 0)

__device__ inline short f2bf(float f) {
    union { float f; unsigned u; } c; c.f = f;
    unsigned u = c.u + 0x7fffu + ((c.u >> 16) & 1u);
    return (short)(u >> 16);
}

// ---------------------------------------------------------------------------
// Convert x and the 4 weight matrices to bf16 (RNE). wq..wf land contiguous.
// ---------------------------------------------------------------------------
__global__ __launch_bounds__(256)
void conv_pack(const float* __restrict__ x,  const float* __restrict__ wq,
               const float* __restrict__ wk, const float* __restrict__ wv,
               const float* __restrict__ wf,
               short* __restrict__ xb,  short* __restrict__ wqb,
               short* __restrict__ wkb, short* __restrict__ wvb,
               short* __restrict__ wfb)
{
    int i = blockIdx.x * 256 + threadIdx.x;
    const float* s; short* d; int o;
    if (i < 2097152) { s = x; d = xb; o = i; }
    else {
        int j = i - 2097152; int wsel = j >> 18; o = j & 262143;
        s = wsel == 0 ? wq : wsel == 1 ? wk : wsel == 2 ? wv : wf;
        d = wsel == 0 ? wqb : wsel == 1 ? wkb : wsel == 2 ? wvb : wfb;
    }
    float4 v = ((const float4*)s)[o];
    s16x4 r; r.x = f2bf(v.x); r.y = f2bf(v.y); r.z = f2bf(v.z); r.w = f2bf(v.w);
    ((s16x4*)d)[o] = r;
}

// ---------------------------------------------------------------------------
// Per-lane mask column words. Bit r of word(lane) =
// mask[bb][grp*32+(lane&31)][tile*64 + (r&3)+8*((r>>2)&3)+32*(r>>4)+4*(lane>>5)]
// (coalesced int4 reads; R8/R15-proven)
// ---------------------------------------------------------------------------
__global__ __launch_bounds__(256)
void conv_maskcol(const int* __restrict__ m, unsigned* __restrict__ o)
{
    int gid = blockIdx.x * 256 + threadIdx.x;      // 2048 blocks -> 524288
    int lane = gid & 63;
    int tile = (gid >> 6) & 31;
    int grp  = (gid >> 11) & 63;
    int bb   = gid >> 17;
    int qrow = grp * 32 + (lane & 31);
    int h = lane >> 5;
    const int* base = m + (size_t)bb * S * S + (size_t)qrow * S + tile * 64 + 4 * h;
    unsigned wbits = 0;
#pragma unroll
    for (int a = 0; a < 8; ++a) {
        int4 v = *(const int4*)(base + 8 * (a & 3) + 32 * (a >> 2));
        wbits |= (v.x != 0 ? 1u : 0u) << (4 * a);
        wbits |= (v.y != 0 ? 1u : 0u) << (4 * a + 1);
        wbits |= (v.z != 0 ? 1u : 0u) << (4 * a + 2);
        wbits |= (v.w != 0 ? 1u : 0u) << (4 * a + 3);
    }
    o[gid] = wbits;
}

// ---------------------------------------------------------------------------
// Fused QKV GEMM v2: 256x128 tile, BK=32, 3-buffer LDS pipeline with 2-K-tile
// lookahead, counted vmcnt(3), raw s_barrier. 512 threads = 8 waves (4M x 2N).
// grid (32, 24). Epilogue: q*QSCL -> [B,H,S,64]; k -> [B,H,S,64]; v -> [B,H,64,S].
// ---------------------------------------------------------------------------
__global__ __launch_bounds__(512, 2)
void qkv_p3(const short* __restrict__ xb, const short* __restrict__ wcat,
            const float* __restrict__ bq, const float* __restrict__ bk,
            const float* __restrict__ bv,
            short* __restrict__ qo, short* __restrict__ ko, short* __restrict__ vto)
{
    __shared__ char Lds[73728];          // A: 3 x 16KB, B: 3 x 8KB

    const int t = threadIdx.x, lane = t & 63;
    const int wu = __builtin_amdgcn_readfirstlane(t >> 6);   // wave 0..7
    const int lr = lane & 15, lg = lane >> 4;
    const int wr = wu >> 1, wc = wu & 1;
    const int m0 = blockIdx.x * 256, n0 = blockIdx.y * 128;

    // staging: per call 512 thr x 16B = 8KB = 128 rows of 64B.
    const int srow = t >> 2;                       // 0..127
    const int sw   = ((t & 3) ^ (srow & 3)) * 8;   // pre-swizzled col elems
    const short* asrc0 = xb   + (size_t)(m0 + srow) * 1024 + sw;
    const short* bsrc0 = wcat + (size_t)(n0 + srow) * 1024 + sw;

    // frag-read constants
    const int colA  = (lg * 16) ^ ((lr & 3) << 4);   // byte within 64B row
    const int aRowB = (wr * 64 + lr) * 64;
    const int bRowB = (wc * 64 + lr) * 64;

    f32x4 z = {0.f, 0.f, 0.f, 0.f};
    f32x4 acc[4][4];
#pragma unroll
    for (int i = 0; i < 4; ++i)
#pragma unroll
        for (int jj = 0; jj < 4; ++jj) acc[i][jj] = z;

    auto stage = [&](int k2, int buf2) {
        const int kofs = k2 * 32;
        char* ab = Lds + buf2 * 16384 + wu * 1024;
        char* bb = Lds + 49152 + buf2 * 8192 + wu * 1024;
        GLDS16(asrc0 + kofs, ab);
        GLDS16(asrc0 + kofs + 128 * 1024, ab + 8192);
        GLDS16(bsrc0 + kofs, bb);
    };

    // prologue: K0 -> buf0, K1 -> buf1 ; wait K0 (leave K1's 3 in flight)
    stage(0, 0);
    stage(1, 1);
    asm volatile("s_waitcnt vmcnt(3)" ::: "memory");
    __builtin_amdgcn_s_barrier();
    __builtin_amdgcn_sched_barrier(0);

    for (int k = 0; k < 32; ++k) {
        const int buf = k % 3;
        if (k + 2 < 32) stage(k + 2, (k + 2) % 3);

        const char* Ab = Lds + buf * 16384;
        const char* Bb = Lds + 49152 + buf * 8192;
        bf16x8 bfr[4], af[4];
#pragma unroll
        for (int fj = 0; fj < 4; ++fj)
            bfr[fj] = *(const bf16x8*)(Bb + bRowB + fj * 1024 + colA);
#pragma unroll
        for (int fi = 0; fi < 4; ++fi)
            af[fi] = *(const bf16x8*)(Ab + aRowB + fi * 1024 + colA);

        __builtin_amdgcn_s_setprio(1);
#pragma unroll
        for (int fi = 0; fi < 4; ++fi)
#pragma unroll
            for (int fj = 0; fj < 4; ++fj)
                acc[fi][fj] = MFMA16(af[fi], bfr[fj], acc[fi][fj]);
        __builtin_amdgcn_s_setprio(0);

        if (k < 30)       asm volatile("s_waitcnt vmcnt(3)" ::: "memory");
        else if (k == 30) asm volatile("s_waitcnt vmcnt(0)" ::: "memory");
        __builtin_amdgcn_s_barrier();
        __builtin_amdgcn_sched_barrier(0);
    }

    // epilogue (proven form; wr in 0..3)
    const int bb = m0 >> 11;
    const int ssb = (m0 & 2047) + wr * 64 + lg * 4;
    const int mat = n0 >> 10;
    const int nbase = (n0 & 1023) + wc * 64;

    if (mat == 0) {
#pragma unroll
        for (int fj = 0; fj < 4; ++fj) {
            const int nl = nbase + fj * 16 + lr, hh = nl >> 6, hd = nl & 63;
            const float bi = bq[nl];
#pragma unroll
            for (int fi = 0; fi < 4; ++fi)
#pragma unroll
                for (int r = 0; r < 4; ++r)
                    qo[(((size_t)bb * H + hh) * S + ssb + fi * 16 + r) * 64 + hd] =
                        f2bf((acc[fi][fj][r] + bi) * QSCL);
        }
    } else if (mat == 1) {
#pragma unroll
        for (int fj = 0; fj < 4; ++fj) {
            const int nl = nbase + fj * 16 + lr, hh = nl >> 6, hd = nl & 63;
            const float bi = bk[nl];
#pragma unroll
            for (int fi = 0; fi < 4; ++fi)
#pragma unroll
                for (int r = 0; r < 4; ++r)
                    ko[(((size_t)bb * H + hh) * S + ssb + fi * 16 + r) * 64 + hd] =
                        f2bf(acc[fi][fj][r] + bi);
        }
    } else {
#pragma unroll
        for (int fj = 0; fj < 4; ++fj) {
            const int nl = nbase + fj * 16 + lr, hh = nl >> 6, hd = nl & 63;
            const float bi = bv[nl];
#pragma unroll
            for (int fi = 0; fi < 4; ++fi) {
                s16x4 pk;
#pragma unroll
                for (int r = 0; r < 4; ++r) pk[r] = f2bf(acc[fi][fj][r] + bi);
                *(s16x4*)(vto + (((size_t)bb * H + hh) * 64 + hd) * S + ssb + fi * 16) = pk;
            }
        }
    }
}

// ---------------------------------------------------------------------------
// Flash attention v8 @ 4 blocks/CU: swapped-QK 32x32 MFMA, 16 MFMA/tile,
// select-mask from prefetched column word + native exp2, VALU li.
// Grid 1024 = exactly 4 blocks/CU; (256,4) removes the straggler round that
// capped occupancy at 31% under (256,3). VGPR 64 << 128 cap, volatile asm.
// ---------------------------------------------------------------------------
__global__ __launch_bounds__(256, 4)
void attn_mfma8(const short* __restrict__ qg, const short* __restrict__ kg,
                const short* __restrict__ vtg,
                const unsigned* __restrict__ mcol,
                short* __restrict__ hc)
{
    __shared__ short Kl[2][64 * 64];
    __shared__ short Vl[2][64 * 64];

    const int t = threadIdx.x, lane = t & 63;
    const int w = __builtin_amdgcn_readfirstlane(t >> 6);
    const int l31 = lane & 31, h = lane >> 5;

    const int id = blockIdx.x;
    const int xcd = id & 7, j = id >> 3;
    const int bh = xcd + 8 * (j >> 4);
    const int q0 = (j & 15) * 128;
    const int bb = bh >> 4, hh = bh & 15;

    const short* qb  = qg  + (size_t)bh * S * 64;
    const short* kb  = kg  + (size_t)bh * S * 64;
    const short* vtb = vtg + (size_t)bh * 64 * S;
    const unsigned* mc = mcol + ((size_t)(bb * 64 + (q0 >> 5) + w)) * 32 * 64 + lane;

    const int qrow = q0 + w * 32 + l31;
    bf16x8 qf[4];
#pragma unroll
    for (int ds = 0; ds < 4; ++ds)
        qf[ds] = *(const bf16x8*)(qb + (size_t)qrow * 64 + ds * 16 + 8 * h);

    const int sk = t >> 3;                                    // staging row 0..31
    const int soff = (((t & 7) * 16) ^ ((sk & 7) << 4)) >> 1; // pre-swizzled src elem
    const int rbyte = l31 * 128;
    const int sz = (lane & 7) << 4;

    f32x16 z16;
#pragma unroll
    for (int i = 0; i < 16; ++i) z16[i] = 0.f;
    f32x16 O0 = z16, O1 = z16;
    float li = 0.f;

    auto issue_stage = [&](int kt, int buf) {
        const short* ks0 = kb + (size_t)(kt + sk) * 64 + soff;
        const short* vs0 = vtb + (size_t)sk * S + kt + soff;
        char* kB = (char*)&Kl[buf][0] + w * 1024;
        char* vB = (char*)&Vl[buf][0] + w * 1024;
        GLDS16(ks0, kB);
        GLDS16(ks0 + 32 * 64, kB + 4096);
        GLDS16(vs0, vB);
        GLDS16(vs0 + (size_t)32 * S, vB + 4096);
    };

    unsigned mcw = mc[0];
    issue_stage(0, 0);
    __syncthreads();

    for (int tile = 0; tile < 32; ++tile) {
        const int cur = tile & 1;
        unsigned mcn = 0;
        if (tile < 31) {
            issue_stage((tile + 1) * 64, cur ^ 1);
            mcn = mc[(tile + 1) * 64];
        }

        // ---- QK^T (swapped): lane owns q-row l31; acc starts at 0
        f32x16 s0 = z16, s1 = z16;
        const char* Kb = (const char*)&Kl[cur][0];
#pragma unroll
        for (int ds = 0; ds < 4; ++ds) {
            const int off = ((ds * 32 + h * 16) ^ sz);
            bf16x8 a0 = *(const bf16x8*)(Kb + rbyte + off);
            bf16x8 a1 = *(const bf16x8*)(Kb + 4096 + rbyte + off);
            s0 = MFMA32(a0, qf[ds], s0);
            s1 = MFMA32(a1, qf[ds], s1);
        }

        // ---- p = 2^(mask ? s : -inf) ; li += p ; pack ; PV
        const char* Vb = (const char*)&Vl[cur][0];
#pragma unroll
        for (int ks = 0; ks < 4; ++ks) {
            const int rb = (ks < 2) ? ks * 8 : (ks - 2) * 8;
            const int wb = (ks < 2) ? rb : 16 + rb;
            float pv[8];
#pragma unroll
            for (int jj = 0; jj < 8; ++jj) {
                float sv = (ks < 2) ? s0[rb + jj] : s1[rb + jj];
                sv = (mcw & (1u << (wb + jj))) ? sv : -INFINITY;
                pv[jj] = EXP2(sv);
                li += pv[jj];
            }
            int w0a, w1a, w0b, w1b;
            asm volatile("v_cvt_pk_bf16_f32 %0, %1, %2" : "=v"(w0a) : "v"(pv[0]), "v"(pv[1]));
            asm volatile("v_cvt_pk_bf16_f32 %0, %1, %2" : "=v"(w1a) : "v"(pv[2]), "v"(pv[3]));
            asm volatile("v_cvt_pk_bf16_f32 %0, %1, %2" : "=v"(w0b) : "v"(pv[4]), "v"(pv[5]));
            asm volatile("v_cvt_pk_bf16_f32 %0, %1, %2" : "=v"(w1b) : "v"(pv[6]), "v"(pv[7]));
            asm volatile("v_permlane32_swap_b32 %0, %1" : "+v"(w0a), "+v"(w0b));
            asm volatile("v_permlane32_swap_b32 %0, %1" : "+v"(w1a), "+v"(w1b));
            union { int i[4]; bf16x8 v; } pf;
            pf.i[0] = w0a; pf.i[1] = w1a; pf.i[2] = w0b; pf.i[3] = w1b;

            const int koff = ((ks * 32 + h * 16) ^ sz);
            bf16x8 v0 = *(const bf16x8*)(Vb + rbyte + koff);
            bf16x8 v1 = *(const bf16x8*)(Vb + 4096 + rbyte + koff);
            O0 = MFMA32(pf.v, v0, O0);
            O1 = MFMA32(pf.v, v1, O1);
        }

        if (tile < 31) mcw = mcn;
        __syncthreads();
    }

    // ---- epilogue: combine half-row sums, broadcast 1/li to output regs
    li += __shfl_xor(li, 32);             // full row-sum for q-row l31
    const float inv = 1.f / li;
    const int ib = __builtin_bit_cast(int, inv);
    const size_t outb = (size_t)bb * S * D + (size_t)hh * 64;
#pragma unroll
    for (int r = 0; r < 16; ++r) {
        const int qp = (r & 3) + 8 * (r >> 2);
        const int vlo = __builtin_amdgcn_readlane(ib, qp);
        const int vhi = __builtin_amdgcn_readlane(ib, qp + 4);
        const float ir = h ? __builtin_bit_cast(float, vhi)
                           : __builtin_bit_cast(float, vlo);
        const int row = q0 + w * 32 + qp + 4 * h;
        hc[outb + (size_t)row * D + l31]      = f2bf(O0[r] * ir);
        hc[outb + (size_t)row * D + 32 + l31] = f2bf(O1[r] * ir);
    }
}

// ---------------------------------------------------------------------------
// Output projection, 128x128 tile, fp32 out. grid (64, 8); block 256.
// ---------------------------------------------------------------------------
__global__ __launch_bounds__(256, 3)
void proj_mfma(const short* __restrict__ hb, const short* __restrict__ wfb,
               const float* __restrict__ bfp, float* __restrict__ out)
{
    __shared__ short As[128 * 64];
    __shared__ short Bs[128 * 64];
    const int t = threadIdx.x, lane = t & 63;
    const int w = __builtin_amdgcn_readfirstlane(t >> 6);
    const int lr = lane & 15, lg = lane >> 4;
    const int wr = w >> 1, wc = w & 1;
    const int m0 = blockIdx.x * 128, n0 = blockIdx.y * 128;

    const int srow = t >> 3;
    const int scol = ((t & 7) ^ (srow & 7)) * 8;
    const short* asrc = hb  + (size_t)(m0 + srow) * 1024 + scol;
    const short* bsrc = wfb + (size_t)(n0 + srow) * 1024 + scol;
    char* aldst = (char*)As + w * 1024;
    char* bldst = (char*)Bs + w * 1024;

    f32x4 z = {0.f, 0.f, 0.f, 0.f};
    f32x4 acc[4][4];
#pragma unroll
    for (int i = 0; i < 4; ++i)
#pragma unroll
        for (int jj = 0; jj < 4; ++jj) acc[i][jj] = z;

    for (int kt = 0; kt < 1024; kt += 64) {
        __syncthreads();
        GLDS16(asrc + kt,             aldst);
        GLDS16(asrc + kt + 32 * 1024, aldst + 4096);
        GLDS16(asrc + kt + 64 * 1024, aldst + 8192);
        GLDS16(asrc + kt + 96 * 1024, aldst + 12288);
        GLDS16(bsrc + kt,             bldst);
        GLDS16(bsrc + kt + 32 * 1024, bldst + 4096);
        GLDS16(bsrc + kt + 64 * 1024, bldst + 8192);
        GLDS16(bsrc + kt + 96 * 1024, bldst + 12288);
        __syncthreads();
#pragma unroll
        for (int ks = 0; ks < 2; ++ks) {
            bf16x8 af[4], bfr[4];
#pragma unroll
            for (int fi = 0; fi < 4; ++fi) {
                const int ra = wr * 64 + fi * 16 + lr;
                af[fi] = *(const bf16x8*)((const char*)As + ra * 128 +
                          ((ks * 64 + lg * 16) ^ ((ra & 7) << 4)));
                const int rb = wc * 64 + fi * 16 + lr;
                bfr[fi] = *(const bf16x8*)((const char*)Bs + rb * 128 +
                          ((ks * 64 + lg * 16) ^ ((rb & 7) << 4)));
            }
#pragma unroll
            for (int fi = 0; fi < 4; ++fi)
#pragma unroll
                for (int fj = 0; fj < 4; ++fj)
                    acc[fi][fj] = MFMA16(af[fi], bfr[fj], acc[fi][fj]);
        }
    }

#pragma unroll
    for (int fj = 0; fj < 4; ++fj) {
        const int nl = n0 + wc * 64 + fj * 16 + lr;
        const float bi = bfp[nl];
#pragma unroll
        for (int fi = 0; fi < 4; ++fi)
#pragma unroll
            for (int r = 0; r < 4; ++r)
                out[(size_t)(m0 + wr * 64 + fi * 16 + lg * 4 + r) * 1024 + nl] =
                    acc[fi][fj][r] + bi;
    }
}

// ---------------------------------------------------------------------------
extern "C" void kernel_launch(void* const* d_in, const int* in_sizes, int n_in,
                              void* d_out, int out_size, void* d_ws, size_t ws_size,
                              hipStream_t stream)
{
    const float* x  = (const float*)d_in[0];
    const int* mask = (const int*)d_in[1];
    const float* Wq = (const float*)d_in[2];
    const float* bq = (const float*)d_in[3];
    const float* Wk = (const float*)d_in[4];
    const float* bk = (const float*)d_in[5];
    const float* Wv = (const float*)d_in[6];
    const float* bv = (const float*)d_in[7];
    const float* Wf = (const float*)d_in[8];
    const float* bf = (const float*)d_in[9];
    float* out = (float*)d_out;

    char* p = (char*)d_ws;
    short* xb  = (short*)p; p += 16777216;                       // x bf16
    short* wqb = (short*)p; p += 2097152;                        // [Wq;Wk;Wv;Wf] bf16
    short* wkb = (short*)p; p += 2097152;
    short* wvb = (short*)p; p += 2097152;
    short* wfb = (short*)p; p += 2097152;
    short* qb  = (short*)p; p += 16777216;                       // [B,H,S,64]
    short* kb  = (short*)p; p += 16777216;                       // [B,H,S,64]
    short* vtb = (short*)p; p += 16777216;                       // [B,H,64,S]
    short* hcb = (short*)p; p += 16777216;                       // [B,S,D]
    unsigned* mcol = (unsigned*)p; p += 2097152;                 // mask column words

    conv_pack<<<12288, 256, 0, stream>>>(x, Wq, Wk, Wv, Wf, xb, wqb, wkb, wvb, wfb);
    conv_maskcol<<<2048, 256, 0, stream>>>(mask, mcol);
    qkv_p3<<<dim3(32, 24), 512, 0, stream>>>(xb, wqb, bq, bk, bv, qb, kb, vtb);
    attn_mfma8<<<1024, 256, 0, stream>>>(qb, kb, vtb, mcol, hcb);
    proj_mfma<<<dim3(64, 8), 256, 0, stream>>>(hcb, wfb, bf, out);
}